// Round 2
// baseline (17178.674 us; speedup 1.0000x reference)
//
#include <hip/hip_runtime.h>
#include <cstdint>

#define NBATCH 16
#define NPTS   100000
#define NPOINT 1024
#define GPB    16            // blocks per batch
#define TPB    256           // threads per block
#define STRIDE (GPB * TPB)   // 4096 threads per batch
#define KPT    25            // ceil(NPTS / STRIDE)

// d_ws layout:
//   @0     : float  sums[16][4]       (256 B)   — batch coordinate sums (atomicAdd)
//   @256   : uint   maxbits[16]       (64 B)    — batch max squared radius (atomicMax)
//   @4096  : u64    fast[2][256]      (4096 B)  — per-(parity,batch,block) msg, XCD-L2 path
//   @8192  : u64    slow[2][256]      (4096 B)  — same msg, agent-scope fallback path
// memset(d_ws, 0, 12288) before launch (harness poisons with 0xAA).

// ---- XCD-L2 communication primitives (fast path) ----
// Plain/sc0 stores land in the XCD's L2 (vector L1 is write-through); sc0 loads
// bypass L1 and read that L2. Coherent ONLY within an XCD — which is why the
// agent-scope slow path always runs in parallel as the correctness guarantee.
__device__ __forceinline__ void fast_store_u64(unsigned long long* p, unsigned long long v) {
    asm volatile("global_store_dwordx2 %0, %1, off sc0" :: "v"(p), "v"(v) : "memory");
}
__device__ __forceinline__ unsigned long long fast_load_u64(const unsigned long long* p) {
    unsigned long long v;
    asm volatile("global_load_dwordx2 %0, %1, off sc0\n\ts_waitcnt vmcnt(0)"
                 : "=v"(v) : "v"(p) : "memory");
    return v;
}

// ---------------- precompute: per-batch coordinate sums ----------------
__global__ __launch_bounds__(256) void sum_kernel(const float* __restrict__ xyz,
                                                  float* __restrict__ sums) {
    const int b   = blockIdx.x & 15;
    const int sub = blockIdx.x >> 4;      // 8 blocks per batch
    const float* P = xyz + (size_t)b * NPTS * 3;
    float sx = 0.f, sy = 0.f, sz = 0.f;
    for (int i = sub * TPB + threadIdx.x; i < NPTS; i += 8 * TPB) {
        sx += P[i * 3 + 0];
        sy += P[i * 3 + 1];
        sz += P[i * 3 + 2];
    }
    #pragma unroll
    for (int off = 32; off; off >>= 1) {
        sx += __shfl_xor(sx, off);
        sy += __shfl_xor(sy, off);
        sz += __shfl_xor(sz, off);
    }
    __shared__ float r[3][4];
    const int wave = threadIdx.x >> 6, lane = threadIdx.x & 63;
    if (lane == 0) { r[0][wave] = sx; r[1][wave] = sy; r[2][wave] = sz; }
    __syncthreads();
    if (threadIdx.x == 0) {
        atomicAdd(&sums[b * 4 + 0], r[0][0] + r[0][1] + r[0][2] + r[0][3]);
        atomicAdd(&sums[b * 4 + 1], r[1][0] + r[1][1] + r[1][2] + r[1][3]);
        atomicAdd(&sums[b * 4 + 2], r[2][0] + r[2][1] + r[2][2] + r[2][3]);
    }
}

// ---------------- precompute: per-batch max squared radius ----------------
__global__ __launch_bounds__(256) void max_kernel(const float* __restrict__ xyz,
                                                  const float* __restrict__ sums,
                                                  unsigned* __restrict__ maxbits) {
    const int b   = blockIdx.x & 15;
    const int sub = blockIdx.x >> 4;
    const float* P = xyz + (size_t)b * NPTS * 3;
    const float mx = sums[b * 4 + 0] / (float)NPTS;
    const float my = sums[b * 4 + 1] / (float)NPTS;
    const float mz = sums[b * 4 + 2] / (float)NPTS;
    float best = 0.f;
    for (int i = sub * TPB + threadIdx.x; i < NPTS; i += 8 * TPB) {
        float dx = P[i * 3 + 0] - mx;
        float dy = P[i * 3 + 1] - my;
        float dz = P[i * 3 + 2] - mz;
        float d = dx * dx + dy * dy + dz * dz;
        best = fmaxf(best, d);
    }
    #pragma unroll
    for (int off = 32; off; off >>= 1) best = fmaxf(best, __shfl_xor(best, off));
    __shared__ float r[4];
    const int wave = threadIdx.x >> 6, lane = threadIdx.x & 63;
    if (lane == 0) r[wave] = best;
    __syncthreads();
    if (threadIdx.x == 0) {
        float m = fmaxf(fmaxf(r[0], r[1]), fmaxf(r[2], r[3]));
        atomicMax(&maxbits[b], __float_as_uint(m));  // d >= 0 -> bits order-preserving
    }
}

// ---------------- main: farthest point sampling + fused gather/normalize ----------------
// Message word: [63:54] = seq (iteration+1), [53:22] = float bits of max distance (>=0),
//               [21:0]  = 0x3FFFFF - point_index  (max-compare => smallest index on ties,
//                         matching np.argmax first-occurrence)
__global__ __launch_bounds__(256) void fps_kernel(const float* __restrict__ xyz,
                                                  const float* __restrict__ cmap,
                                                  const int* __restrict__ init_far,
                                                  const unsigned* __restrict__ maxbits,
                                                  unsigned long long* __restrict__ fast,
                                                  unsigned long long* __restrict__ slow,
                                                  float* __restrict__ out) {
    const int b   = blockIdx.x & 15;   // batch: all 16 blocks of a batch land on XCD b%8
    const int g   = blockIdx.x >> 4;   // block-in-batch 0..15
    const int tid = threadIdx.x;
    const int tl  = g * TPB + tid;     // batch-local lane 0..4095
    const float* P = xyz + (size_t)b * NPTS * 3;

    // register-resident points + running distances
    float px[KPT], py[KPT], pz[KPT], pd[KPT];
    #pragma unroll
    for (int k = 0; k < KPT; ++k) {
        const int p = tl + k * STRIDE;
        const bool v = p < NPTS;
        px[k] = v ? P[p * 3 + 0] : 0.f;
        py[k] = v ? P[p * 3 + 1] : 0.f;
        pz[k] = v ? P[p * 3 + 2] : 0.f;
        pd[k] = v ? 1e10f : -1.0f;     // masked slots never win (real d >= 0)
    }

    __shared__ unsigned long long lds_key[4];
    __shared__ int lds_win;
    const int wave = tid >> 6, lane = tid & 63;

    int cur = init_far[b];
    const float sb = sqrtf(__uint_as_float(maxbits[b]));
    const bool writer = (g == 0) && (tid == 0);

    for (int i = 0; i < NPOINT; ++i) {
        const float cx = P[cur * 3 + 0];
        const float cy = P[cur * 3 + 1];
        const float cz = P[cur * 3 + 2];

        if (writer) {
            const float c = cmap[(size_t)b * NPTS + cur];
            float* o = out + ((size_t)b * NPOINT + i) * 4;
            o[0] = c;
            o[1] = cx / sb;
            o[2] = cy / sb;
            o[3] = cz / sb;
        }
        if (i == NPOINT - 1) break;

        // min-update + per-thread argmax (exact fp order match with numpy: no fma)
        float best = -1.0f;
        int bestk = 0;
        {
            #pragma clang fp contract(off)
            #pragma unroll
            for (int k = 0; k < KPT; ++k) {
                float dx = px[k] - cx;
                float dy = py[k] - cy;
                float dz = pz[k] - cz;
                float dist = dx * dx + dy * dy;
                dist = dist + dz * dz;
                float nd = fminf(pd[k], dist);
                pd[k] = nd;
                if (nd > best) { best = nd; bestk = k; }  // strict > keeps smallest k
            }
        }
        const unsigned pidx = (unsigned)(tl + bestk * STRIDE);
        unsigned long long key =
            ((unsigned long long)__float_as_uint(best) << 22) |
            (unsigned long long)(0x3FFFFFu - pidx);

        // wave argmax
        #pragma unroll
        for (int off = 32; off; off >>= 1) {
            unsigned long long o2 = __shfl_xor(key, off);
            key = o2 > key ? o2 : key;
        }
        if (lane == 0) lds_key[wave] = key;
        __syncthreads();   // syncA

        const int base = (i & 1) * 256 + b * GPB;
        const unsigned long long want = (unsigned long long)(i + 1);

        if (wave == 0) {
            // POLLER wave: no outstanding stores of its own -> vmcnt waits are pure poll RT
            unsigned long long v = 0;
            if (lane < GPB) {
                unsigned long long* fp = &fast[base + lane];
                unsigned long long* sp = &slow[base + lane];
                int tries = 0;
                for (;;) {
                    v = fast_load_u64(fp);
                    if ((v >> 54) >= want) break;
                    ++tries;
                    if (tries > 128) {   // correctness fallback: agent-scope slot
                        v = __hip_atomic_load(sp, __ATOMIC_RELAXED, __HIP_MEMORY_SCOPE_AGENT);
                        if ((v >> 54) >= want) break;
                        __builtin_amdgcn_s_sleep(2);
                    } else if (tries > 32) {
                        __builtin_amdgcn_s_sleep(1);
                    }
                }
            }
            #pragma unroll
            for (int off = 8; off; off >>= 1) {
                unsigned long long o2 = __shfl_xor(v, off);
                v = o2 > v ? o2 : v;
            }
            if (lane == 0)
                lds_win = (int)(0x3FFFFFu - (unsigned)(v & 0x3FFFFFu));
        } else if (wave == 1) {
            // STORER wave: block-reduce from LDS, then publish fast (XCD L2) + slow (agent)
            unsigned long long kb = lds_key[0];
            kb = lds_key[1] > kb ? lds_key[1] : kb;
            kb = lds_key[2] > kb ? lds_key[2] : kb;
            kb = lds_key[3] > kb ? lds_key[3] : kb;
            const unsigned long long send = kb | (want << 54);
            if (lane == 0) {
                fast_store_u64(&fast[base + g], send);
                __hip_atomic_store(&slow[base + g], send,
                                   __ATOMIC_RELAXED, __HIP_MEMORY_SCOPE_AGENT);
            }
        }
        __syncthreads();   // syncB
        cur = lds_win;
    }
}

extern "C" void kernel_launch(void* const* d_in, const int* in_sizes, int n_in,
                              void* d_out, int out_size, void* d_ws, size_t ws_size,
                              hipStream_t stream) {
    const float* mesh = (const float*)d_in[0];
    const float* cmap = (const float*)d_in[1];
    const int* init   = (const int*)d_in[2];
    float* out = (float*)d_out;

    char* ws = (char*)d_ws;
    float* sums               = (float*)ws;
    unsigned* maxbits         = (unsigned*)(ws + 256);
    unsigned long long* fastS = (unsigned long long*)(ws + 4096);
    unsigned long long* slowS = (unsigned long long*)(ws + 8192);

    hipMemsetAsync(d_ws, 0, 12288, stream);
    sum_kernel<<<dim3(128), dim3(TPB), 0, stream>>>(mesh, sums);
    max_kernel<<<dim3(128), dim3(TPB), 0, stream>>>(mesh, sums, maxbits);
    fps_kernel<<<dim3(256), dim3(TPB), 0, stream>>>(mesh, cmap, init, maxbits, fastS, slowS, out);
}

// Round 3
// 6104.490 us; speedup vs baseline: 2.8141x; 2.8141x over previous
//
#include <hip/hip_runtime.h>
#include <cstdint>

#define NBATCH 16
#define NPTS   100000
#define NPOINT 1024
#define GPB    16            // blocks per batch
#define TPB    256           // threads per block (4 waves)
#define WPB    4             // waves per block
#define NSLOT  (GPB * WPB)   // 64 wave-slots per batch
#define STRIDE (GPB * TPB)   // 4096 threads per batch
#define KPT    25            // ceil(NPTS / STRIDE)

// d_ws layout:
//   @0     : float  sums[16][4]           (256 B)  — batch coordinate sums (atomicAdd)
//   @256   : uint   maxbits[16]           (64 B)   — batch max squared radius (atomicMax)
//   @4096  : u64    slots[2][16][64]      (16 KB)  — per-(parity,batch,wave) argmax message
// memset(d_ws, 0, 20480) before fps launch (harness poisons with 0xAA; poisoned seq
// field would false-accept, so the clear is mandatory).

// ---------------- precompute: per-batch coordinate sums ----------------
__global__ __launch_bounds__(256) void sum_kernel(const float* __restrict__ xyz,
                                                  float* __restrict__ sums) {
    const int b   = blockIdx.x & 15;
    const int sub = blockIdx.x >> 4;      // 8 blocks per batch
    const float* P = xyz + (size_t)b * NPTS * 3;
    float sx = 0.f, sy = 0.f, sz = 0.f;
    for (int i = sub * TPB + threadIdx.x; i < NPTS; i += 8 * TPB) {
        sx += P[i * 3 + 0];
        sy += P[i * 3 + 1];
        sz += P[i * 3 + 2];
    }
    #pragma unroll
    for (int off = 32; off; off >>= 1) {
        sx += __shfl_xor(sx, off);
        sy += __shfl_xor(sy, off);
        sz += __shfl_xor(sz, off);
    }
    __shared__ float r[3][4];
    const int wave = threadIdx.x >> 6, lane = threadIdx.x & 63;
    if (lane == 0) { r[0][wave] = sx; r[1][wave] = sy; r[2][wave] = sz; }
    __syncthreads();
    if (threadIdx.x == 0) {
        atomicAdd(&sums[b * 4 + 0], r[0][0] + r[0][1] + r[0][2] + r[0][3]);
        atomicAdd(&sums[b * 4 + 1], r[1][0] + r[1][1] + r[1][2] + r[1][3]);
        atomicAdd(&sums[b * 4 + 2], r[2][0] + r[2][1] + r[2][2] + r[2][3]);
    }
}

// ---------------- precompute: per-batch max squared radius ----------------
__global__ __launch_bounds__(256) void max_kernel(const float* __restrict__ xyz,
                                                  const float* __restrict__ sums,
                                                  unsigned* __restrict__ maxbits) {
    const int b   = blockIdx.x & 15;
    const int sub = blockIdx.x >> 4;
    const float* P = xyz + (size_t)b * NPTS * 3;
    const float mx = sums[b * 4 + 0] / (float)NPTS;
    const float my = sums[b * 4 + 1] / (float)NPTS;
    const float mz = sums[b * 4 + 2] / (float)NPTS;
    float best = 0.f;
    for (int i = sub * TPB + threadIdx.x; i < NPTS; i += 8 * TPB) {
        float dx = P[i * 3 + 0] - mx;
        float dy = P[i * 3 + 1] - my;
        float dz = P[i * 3 + 2] - mz;
        float d = dx * dx + dy * dy + dz * dz;
        best = fmaxf(best, d);
    }
    #pragma unroll
    for (int off = 32; off; off >>= 1) best = fmaxf(best, __shfl_xor(best, off));
    __shared__ float r[4];
    const int wave = threadIdx.x >> 6, lane = threadIdx.x & 63;
    if (lane == 0) r[wave] = best;
    __syncthreads();
    if (threadIdx.x == 0) {
        float m = fmaxf(fmaxf(r[0], r[1]), fmaxf(r[2], r[3]));
        atomicMax(&maxbits[b], __float_as_uint(m));  // d >= 0 -> bits order-preserving
    }
}

// ---------------- main: barrier-free FPS + fused gather/normalize ----------------
// Message word: [63:54] = seq (iteration+1), [53:22] = float bits of max distance (>=0),
//               [21:0]  = 0x3FFFFF - point_index  (max-compare => smallest index on ties,
//                         matching np.argmax first-occurrence)
// No __syncthreads in the loop: each wave publishes its own wave-max slot and polls all
// 64 slots of its batch. Lag<=1 proof: a seq i+3 store (same parity as seq i+1) requires
// its wave to have completed the i+1 poll, which requires all waves stored i+1, which
// requires all waves completed the i poll — so nobody still polling seq i+1 can see it.
__global__ __launch_bounds__(256) void fps_kernel(const float* __restrict__ xyz,
                                                  const float* __restrict__ cmap,
                                                  const int* __restrict__ init_far,
                                                  const unsigned* __restrict__ maxbits,
                                                  unsigned long long* __restrict__ slots,
                                                  float* __restrict__ out) {
    const int b   = blockIdx.x & 15;   // batch
    const int g   = blockIdx.x >> 4;   // block-in-batch 0..15
    const int tid = threadIdx.x;
    const int tl  = g * TPB + tid;     // batch-local lane 0..4095
    const float* P = xyz + (size_t)b * NPTS * 3;

    // register/AGPR-resident points + running distances
    float px[KPT], py[KPT], pz[KPT], pd[KPT];
    #pragma unroll
    for (int k = 0; k < KPT; ++k) {
        const int p = tl + k * STRIDE;
        const bool v = p < NPTS;
        px[k] = v ? P[p * 3 + 0] : 0.f;
        py[k] = v ? P[p * 3 + 1] : 0.f;
        pz[k] = v ? P[p * 3 + 2] : 0.f;
        pd[k] = v ? 1e10f : -1.0f;     // masked slots never win (real d >= 0)
    }

    const int wave = tid >> 6, lane = tid & 63;
    const int myslot = g * WPB + wave;           // 0..63, unique per wave in the batch
    unsigned long long* const batch_slots0 = slots + (size_t)b * NSLOT;
    unsigned long long* const batch_slots1 = slots + 1024 + (size_t)b * NSLOT;

    int cur = init_far[b];
    const float sb = sqrtf(__uint_as_float(maxbits[b]));
    const bool writer = (g == 0) && (tid == 0);

    for (int i = 0; i < NPOINT; ++i) {
        // centroid coords: same address across the wave -> broadcast load (L2-hot)
        const float cx = P[cur * 3 + 0];
        const float cy = P[cur * 3 + 1];
        const float cz = P[cur * 3 + 2];

        if (writer) {
            const float c = cmap[(size_t)b * NPTS + cur];
            float* o = out + ((size_t)b * NPOINT + i) * 4;
            o[0] = c;
            o[1] = cx / sb;
            o[2] = cy / sb;
            o[3] = cz / sb;
        }
        if (i == NPOINT - 1) break;

        // min-update + per-thread argmax (exact fp order match with numpy: no fma)
        float best = -1.0f;
        int bestk = 0;
        {
            #pragma clang fp contract(off)
            #pragma unroll
            for (int k = 0; k < KPT; ++k) {
                float dx = px[k] - cx;
                float dy = py[k] - cy;
                float dz = pz[k] - cz;
                float dist = dx * dx + dy * dy;
                dist = dist + dz * dz;
                float nd = fminf(pd[k], dist);
                pd[k] = nd;
                if (nd > best) { best = nd; bestk = k; }  // strict > keeps smallest k
            }
        }
        const unsigned pidx = (unsigned)(tl + bestk * STRIDE);
        unsigned long long key =
            ((unsigned long long)__float_as_uint(best) << 22) |
            (unsigned long long)(0x3FFFFFu - pidx);

        // wave argmax (butterfly: all lanes end with the wave max)
        #pragma unroll
        for (int off = 32; off; off >>= 1) {
            unsigned long long o2 = __shfl_xor(key, off);
            key = o2 > key ? o2 : key;
        }

        const unsigned long long want = (unsigned long long)(i + 1);
        unsigned long long* const bs = (i & 1) ? batch_slots1 : batch_slots0;

        // publish this wave's max (lane 0), then every lane polls one of the 64 slots
        if (lane == 0)
            __hip_atomic_store(&bs[myslot], key | (want << 54),
                               __ATOMIC_RELAXED, __HIP_MEMORY_SCOPE_AGENT);

        unsigned long long v;
        {
            unsigned long long* sp = &bs[lane];
            int tries = 0;
            for (;;) {
                v = __hip_atomic_load(sp, __ATOMIC_RELAXED, __HIP_MEMORY_SCOPE_AGENT);
                if ((v >> 54) >= want) break;
                if (++tries > 48) __builtin_amdgcn_s_sleep(1);
            }
        }
        // all slots carry identical seq bits here, so u64 max == key max
        #pragma unroll
        for (int off = 32; off; off >>= 1) {
            unsigned long long o2 = __shfl_xor(v, off);
            v = o2 > v ? o2 : v;
        }
        cur = (int)(0x3FFFFFu - (unsigned)(v & 0x3FFFFFu));
    }
}

extern "C" void kernel_launch(void* const* d_in, const int* in_sizes, int n_in,
                              void* d_out, int out_size, void* d_ws, size_t ws_size,
                              hipStream_t stream) {
    const float* mesh = (const float*)d_in[0];
    const float* cmap = (const float*)d_in[1];
    const int* init   = (const int*)d_in[2];
    float* out = (float*)d_out;

    char* ws = (char*)d_ws;
    float* sums               = (float*)ws;
    unsigned* maxbits         = (unsigned*)(ws + 256);
    unsigned long long* slots = (unsigned long long*)(ws + 4096);

    hipMemsetAsync(d_ws, 0, 20480, stream);
    sum_kernel<<<dim3(128), dim3(TPB), 0, stream>>>(mesh, sums);
    max_kernel<<<dim3(128), dim3(TPB), 0, stream>>>(mesh, sums, maxbits);
    fps_kernel<<<dim3(256), dim3(TPB), 0, stream>>>(mesh, cmap, init, maxbits, slots, out);
}

// Round 4
// 3561.798 us; speedup vs baseline: 4.8230x; 1.7139x over previous
//
#include <hip/hip_runtime.h>
#include <cstdint>

#define NBATCH 16
#define NPTS   100000
#define NPOINT 1024
#define GPB    16            // blocks per batch
#define TPB    256           // threads per block (4 waves)
#define WPB    4
#define STRIDE (GPB * TPB)   // 4096 threads per batch
#define KPT    25            // ceil(NPTS / STRIDE)

typedef unsigned long long u64;

// d_ws layout:
//   @0     : float  sums[16][4]          (256 B)  — batch coordinate sums (atomicAdd)
//   @256   : uint   maxbits[16]          (64 B)   — batch max squared radius (atomicMax)
//   @4096  : u64    slots[2][16][16][4]  (16 KB)  — 32-B message per (parity,batch,block):
//              w0 = key | seq<<54   (key = distbits<<22 | (0x3FFFFF - idx))
//              w1 = xbits | ybits<<32
//              w2 = zbits | seq<<32 (back-seq validates the payload snapshot)
//              w3 = unused
// memset(d_ws, 0, 20480) before fps launch (poisoned seq would false-accept).

// coalesced device-coherent plain load (sc0 sc1 -> read at the device coherence point)
__device__ __forceinline__ u64 plain_load_u64(const u64* p) {
    u64 v;
    asm volatile("global_load_dwordx2 %0, %1, off sc0 sc1\n\ts_waitcnt vmcnt(0)"
                 : "=v"(v) : "v"(p) : "memory");
    return v;
}

// ---------------- precompute: per-batch coordinate sums ----------------
__global__ __launch_bounds__(256) void sum_kernel(const float* __restrict__ xyz,
                                                  float* __restrict__ sums) {
    const int b   = blockIdx.x & 15;
    const int sub = blockIdx.x >> 4;      // 8 blocks per batch
    const float* P = xyz + (size_t)b * NPTS * 3;
    float sx = 0.f, sy = 0.f, sz = 0.f;
    for (int i = sub * TPB + threadIdx.x; i < NPTS; i += 8 * TPB) {
        sx += P[i * 3 + 0];
        sy += P[i * 3 + 1];
        sz += P[i * 3 + 2];
    }
    #pragma unroll
    for (int off = 32; off; off >>= 1) {
        sx += __shfl_xor(sx, off);
        sy += __shfl_xor(sy, off);
        sz += __shfl_xor(sz, off);
    }
    __shared__ float r[3][4];
    const int wave = threadIdx.x >> 6, lane = threadIdx.x & 63;
    if (lane == 0) { r[0][wave] = sx; r[1][wave] = sy; r[2][wave] = sz; }
    __syncthreads();
    if (threadIdx.x == 0) {
        atomicAdd(&sums[b * 4 + 0], r[0][0] + r[0][1] + r[0][2] + r[0][3]);
        atomicAdd(&sums[b * 4 + 1], r[1][0] + r[1][1] + r[1][2] + r[1][3]);
        atomicAdd(&sums[b * 4 + 2], r[2][0] + r[2][1] + r[2][2] + r[2][3]);
    }
}

// ---------------- precompute: per-batch max squared radius ----------------
__global__ __launch_bounds__(256) void max_kernel(const float* __restrict__ xyz,
                                                  const float* __restrict__ sums,
                                                  unsigned* __restrict__ maxbits) {
    const int b   = blockIdx.x & 15;
    const int sub = blockIdx.x >> 4;
    const float* P = xyz + (size_t)b * NPTS * 3;
    const float mx = sums[b * 4 + 0] / (float)NPTS;
    const float my = sums[b * 4 + 1] / (float)NPTS;
    const float mz = sums[b * 4 + 2] / (float)NPTS;
    float best = 0.f;
    for (int i = sub * TPB + threadIdx.x; i < NPTS; i += 8 * TPB) {
        float dx = P[i * 3 + 0] - mx;
        float dy = P[i * 3 + 1] - my;
        float dz = P[i * 3 + 2] - mz;
        float d = dx * dx + dy * dy + dz * dz;
        best = fmaxf(best, d);
    }
    #pragma unroll
    for (int off = 32; off; off >>= 1) best = fmaxf(best, __shfl_xor(best, off));
    __shared__ float r[4];
    const int wave = threadIdx.x >> 6, lane = threadIdx.x & 63;
    if (lane == 0) r[wave] = best;
    __syncthreads();
    if (threadIdx.x == 0) {
        float m = fmaxf(fmaxf(r[0], r[1]), fmaxf(r[2], r[3]));
        atomicMax(&maxbits[b], __float_as_uint(m));  // d >= 0 -> bits order-preserving
    }
}

// ---------------- main: FPS with coordinate-carrying messages ----------------
// Lag<=1 proof (parity double-buffer): a seq i+3 store (same parity as i+1) requires its
// block to have completed the i+2 poll => all blocks stored i+2 => all blocks completed
// the i+1 poll. So no slot a poller of seq i+1 is watching can ever hold seq i+3.
__global__ __launch_bounds__(256, 1) void fps_kernel(const float* __restrict__ xyz,
                                                     const float* __restrict__ cmap,
                                                     const int* __restrict__ init_far,
                                                     const unsigned* __restrict__ maxbits,
                                                     u64* __restrict__ slots,
                                                     float* __restrict__ out) {
    const int b   = blockIdx.x & 15;   // batch
    const int g   = blockIdx.x >> 4;   // block-in-batch 0..15
    const int tid = threadIdx.x;
    const int wave = tid >> 6, lane = tid & 63;
    const int tl  = g * TPB + tid;     // batch-local lane 0..4095
    const float* P = xyz + (size_t)b * NPTS * 3;

    // register-resident points + running distances (launch_bounds(256,1): VGPR budget 512)
    float px[KPT], py[KPT], pz[KPT], pd[KPT];
    #pragma unroll
    for (int k = 0; k < KPT; ++k) {
        const int p = tl + k * STRIDE;
        const bool v = p < NPTS;
        px[k] = v ? P[p * 3 + 0] : 0.f;
        py[k] = v ? P[p * 3 + 1] : 0.f;
        pz[k] = v ? P[p * 3 + 2] : 0.f;
        pd[k] = v ? 1e10f : -1.0f;     // every lane has >=24 valid points, so best >= 0 always
    }

    __shared__ u64   lkey[WPB];
    __shared__ float lx[WPB], ly[WPB], lz[WPB];
    __shared__ float bcx_s, bcy_s, bcz_s;
    __shared__ int   bcur_s;

    int cur = init_far[b];
    float cx = P[cur * 3 + 0];         // initial centroid coords (only gather in the loop path)
    float cy = P[cur * 3 + 1];
    float cz = P[cur * 3 + 2];
    const float sb = sqrtf(__uint_as_float(maxbits[b]));
    const bool writer = (g == 0) && (tid == 0);

    for (int i = 0; i < NPOINT; ++i) {
        float cmv = 0.f;
        if (writer) cmv = cmap[(size_t)b * NPTS + cur];   // issued early, consumed post-compute

        if (i == NPOINT - 1) {
            if (writer) {
                float* o = out + ((size_t)b * NPOINT + i) * 4;
                o[0] = cmv; o[1] = cx / sb; o[2] = cy / sb; o[3] = cz / sb;
            }
            break;
        }

        // ---- distance update + per-lane argmax (exact fp order match: no fma) ----
        float best = -1.0f, bx = 0.f, by = 0.f, bz = 0.f;
        int bidx = 0;
        {
            #pragma clang fp contract(off)
            #pragma unroll
            for (int k = 0; k < KPT; ++k) {
                float dx = px[k] - cx;
                float dy = py[k] - cy;
                float dz = pz[k] - cz;
                float dist = dx * dx + dy * dy;
                dist = dist + dz * dz;
                float nd = fminf(pd[k], dist);
                pd[k] = nd;
                bool bt = nd > best;                 // strict > : first occurrence wins
                best = bt ? nd : best;
                bx   = bt ? px[k] : bx;
                by   = bt ? py[k] : by;
                bz   = bt ? pz[k] : bz;
                bidx = bt ? (tl + k * STRIDE) : bidx;
            }
        }

        if (writer) {
            float* o = out + ((size_t)b * NPOINT + i) * 4;
            o[0] = cmv; o[1] = cx / sb; o[2] = cy / sb; o[3] = cz / sb;
        }

        // ---- wave argmax (u64 butterfly; inverted idx -> smallest index on ties) ----
        const u64 want = (u64)(i + 1);
        u64 k0 = ((u64)__float_as_uint(best) << 22) | (u64)(0x3FFFFFu - (unsigned)bidx);
        u64 wk = k0;
        #pragma unroll
        for (int off = 32; off; off >>= 1) {
            u64 o2 = __shfl_xor(wk, off);
            wk = o2 > wk ? o2 : wk;
        }
        const int wwl = __ffsll(__ballot(k0 == wk)) - 1;   // wave winner lane
        float wx = __shfl(bx, wwl), wy = __shfl(by, wwl), wz = __shfl(bz, wwl);
        if (lane == 0) { lkey[wave] = wk; lx[wave] = wx; ly[wave] = wy; lz[wave] = wz; }
        __syncthreads();   // syncA

        if (wave == 0) {
            // block reduce over the 4 wave keys (lanes 0..3)
            u64 b0 = (lane < WPB) ? lkey[lane] : 0;
            u64 bk = b0;
            #pragma unroll
            for (int off = 1; off < WPB; off <<= 1) {
                u64 o2 = __shfl_xor(bk, off);
                bk = o2 > bk ? o2 : bk;
            }
            const int wv = __ffsll(__ballot((lane < WPB) && (b0 == bk))) - 1;
            const float mx = lx[wv], my = ly[wv], mz = lz[wv];   // LDS broadcast

            // compose + publish the 32-B message (4 atomic u64 stores, lanes 0..3)
            u64* bs = slots + ((u64)(i & 1) * NBATCH + b) * (GPB * 4);
            u64 msg = 0;
            if (lane == 0)      msg = bk | (want << 54);
            else if (lane == 1) msg = (u64)__float_as_uint(mx) | ((u64)__float_as_uint(my) << 32);
            else if (lane == 2) msg = (u64)__float_as_uint(mz) | (want << 32);
            if (lane < 4)
                __hip_atomic_store(&bs[g * 4 + lane], msg,
                                   __ATOMIC_RELAXED, __HIP_MEMORY_SCOPE_AGENT);

            // ---- poll: atomic gate on w0 (lanes 0..15) + plain payload load (all lanes) ----
            const unsigned want32 = (unsigned)want;
            u64 vA = 0, vB;
            int tries = 0;
            for (;;) {
                if (lane < GPB)
                    vA = __hip_atomic_load(&bs[lane * 4],
                                           __ATOMIC_RELAXED, __HIP_MEMORY_SCOPE_AGENT);
                vB = (tries < 1024)
                        ? plain_load_u64(&bs[lane])   // waits vmcnt(0): drains vA too -> 1 RT
                        : __hip_atomic_load(&bs[lane],
                                            __ATOMIC_RELAXED, __HIP_MEMORY_SCOPE_AGENT);
                const bool okA = (lane >= GPB)     || ((vA >> 54) == want);
                const bool okB = ((lane & 3) != 2) || ((unsigned)(vB >> 32) == want32);
                if (__all(okA && okB)) break;
                if (++tries > 8) __builtin_amdgcn_s_sleep(1);
            }

            // argmax over the 16 gate words (tear-safe atomic values)
            u64 kk = (lane < GPB) ? vA : 0;
            #pragma unroll
            for (int off = 32; off; off >>= 1) {
                u64 o2 = __shfl_xor(kk, off);
                kk = o2 > kk ? o2 : kk;
            }
            const int ws = __ffsll(__ballot((lane < GPB) && (vA == kk))) - 1;  // winner slot
            const float fb_lo = __uint_as_float((unsigned)vB);
            const float fb_hi = __uint_as_float((unsigned)(vB >> 32));
            const float ncx = __shfl(fb_lo, ws * 4 + 1);
            const float ncy = __shfl(fb_hi, ws * 4 + 1);
            const float ncz = __shfl(fb_lo, ws * 4 + 2);
            const int ncur = (int)(0x3FFFFFu - (unsigned)(kk & 0x3FFFFFu));
            if (lane == 0) { bcx_s = ncx; bcy_s = ncy; bcz_s = ncz; bcur_s = ncur; }
        }
        __syncthreads();   // syncB
        cx = bcx_s; cy = bcy_s; cz = bcz_s; cur = bcur_s;
    }
}

extern "C" void kernel_launch(void* const* d_in, const int* in_sizes, int n_in,
                              void* d_out, int out_size, void* d_ws, size_t ws_size,
                              hipStream_t stream) {
    const float* mesh = (const float*)d_in[0];
    const float* cmap = (const float*)d_in[1];
    const int* init   = (const int*)d_in[2];
    float* out = (float*)d_out;

    char* ws = (char*)d_ws;
    float* sums       = (float*)ws;
    unsigned* maxbits = (unsigned*)(ws + 256);
    u64* slots        = (u64*)(ws + 4096);

    hipMemsetAsync(d_ws, 0, 20480, stream);
    sum_kernel<<<dim3(128), dim3(TPB), 0, stream>>>(mesh, sums);
    max_kernel<<<dim3(128), dim3(TPB), 0, stream>>>(mesh, sums, maxbits);
    fps_kernel<<<dim3(256), dim3(TPB), 0, stream>>>(mesh, cmap, init, maxbits, slots, out);
}

// Round 5
// 2003.719 us; speedup vs baseline: 8.5734x; 1.7776x over previous
//
#include <hip/hip_runtime.h>
#include <cstdint>

#define NBATCH 16
#define NPTS   100000
#define NPOINT 1024
#define GPB    16            // blocks per batch
#define TPB    256           // threads per block (4 waves)
#define WPB    4
#define NSUB   16            // sub-blocks per batch in precompute kernels
#define STRIDE (GPB * TPB)   // 4096 threads per batch
#define KPT    25            // points per thread (ceil 100000/4096)
#define NPAIR  13            // KPT packed into float pairs (last slot half-padded)

typedef unsigned long long u64;

// d_ws layout (no memset needed — see per-region notes):
//   @0    : float psum[16][16][4]  (4 KB) — per-(batch,sub) partial coord sums (plain stores)
//   @4096 : uint  pmax[16][16]     (1 KB) — per-(batch,sub) partial max sq-radius (plain stores)
//   @8192 : u64   slots[2][16][16] (4 KB) — per-(parity,batch,block) argmax msg;
//                                           zeroed by max_kernel block 0 (poisoned seq would
//                                           false-accept, so this clear is mandatory)

// ---------------- precompute 1: per-(batch,sub) coordinate sums ----------------
__global__ __launch_bounds__(256) void sum_kernel(const float* __restrict__ xyz,
                                                  float* __restrict__ psum) {
    const int b   = blockIdx.x & 15;
    const int sub = blockIdx.x >> 4;          // 0..15
    const float* P = xyz + (size_t)b * NPTS * 3;
    float sx = 0.f, sy = 0.f, sz = 0.f;
    for (int i = sub * TPB + threadIdx.x; i < NPTS; i += NSUB * TPB) {
        sx += P[i * 3 + 0];
        sy += P[i * 3 + 1];
        sz += P[i * 3 + 2];
    }
    #pragma unroll
    for (int off = 32; off; off >>= 1) {
        sx += __shfl_xor(sx, off);
        sy += __shfl_xor(sy, off);
        sz += __shfl_xor(sz, off);
    }
    __shared__ float r[3][4];
    const int wave = threadIdx.x >> 6, lane = threadIdx.x & 63;
    if (lane == 0) { r[0][wave] = sx; r[1][wave] = sy; r[2][wave] = sz; }
    __syncthreads();
    if (threadIdx.x == 0) {
        float* o = psum + (b * NSUB + sub) * 4;
        o[0] = r[0][0] + r[0][1] + r[0][2] + r[0][3];
        o[1] = r[1][0] + r[1][1] + r[1][2] + r[1][3];
        o[2] = r[2][0] + r[2][1] + r[2][2] + r[2][3];
    }
}

// ---------------- precompute 2: per-(batch,sub) max squared radius + slot clear ----------------
__global__ __launch_bounds__(256) void max_kernel(const float* __restrict__ xyz,
                                                  const float* __restrict__ psum,
                                                  unsigned* __restrict__ pmax,
                                                  u64* __restrict__ slots) {
    if (blockIdx.x == 0) {                    // clear the 512 message slots (2 per thread)
        slots[threadIdx.x] = 0ull;
        slots[threadIdx.x + 256] = 0ull;
    }
    const int b   = blockIdx.x & 15;
    const int sub = blockIdx.x >> 4;
    const float* P = xyz + (size_t)b * NPTS * 3;
    float sx = 0.f, sy = 0.f, sz = 0.f;
    #pragma unroll
    for (int s = 0; s < NSUB; ++s) {          // fixed order: deterministic mean for all blocks
        sx += psum[(b * NSUB + s) * 4 + 0];
        sy += psum[(b * NSUB + s) * 4 + 1];
        sz += psum[(b * NSUB + s) * 4 + 2];
    }
    const float mx = sx / (float)NPTS, my = sy / (float)NPTS, mz = sz / (float)NPTS;
    float best = 0.f;
    for (int i = sub * TPB + threadIdx.x; i < NPTS; i += NSUB * TPB) {
        float dx = P[i * 3 + 0] - mx;
        float dy = P[i * 3 + 1] - my;
        float dz = P[i * 3 + 2] - mz;
        best = fmaxf(best, dx * dx + dy * dy + dz * dz);
    }
    #pragma unroll
    for (int off = 32; off; off >>= 1) best = fmaxf(best, __shfl_xor(best, off));
    __shared__ float r[4];
    const int wave = threadIdx.x >> 6, lane = threadIdx.x & 63;
    if (lane == 0) r[wave] = best;
    __syncthreads();
    if (threadIdx.x == 0)
        pmax[b * NSUB + sub] = __float_as_uint(fmaxf(fmaxf(r[0], r[1]), fmaxf(r[2], r[3])));
}

// ---------------- main: FPS + fused gather/normalize ----------------
// Message word: [63:54] seq (=i+1), [53:22] float bits of max distance (>=0),
//               [21:0]  0x3FFFFF - idx (max-compare => smallest index on ties = np.argmax).
// Parity double-buffer, lag<=1: a seq i+3 store (same parity as i+1) requires its block
// to have finished the i+2 poll => all blocks stored i+2 => all finished the i+1 poll.
__global__ __launch_bounds__(256, 1) void fps_kernel(const float* __restrict__ xyz,
                                                     const float* __restrict__ cmap,
                                                     const int* __restrict__ init_far,
                                                     const unsigned* __restrict__ pmax,
                                                     u64* __restrict__ slots,
                                                     float* __restrict__ out) {
    const int b   = blockIdx.x & 15;   // batch
    const int g   = blockIdx.x >> 4;   // block-in-batch 0..15
    const int tid = threadIdx.x;
    const int wave = tid >> 6, lane = tid & 63;
    const int tl  = g * TPB + tid;     // batch-local lane 0..4095
    const float* P = xyz + (size_t)b * NPTS * 3;

    // s_obj: deterministic reduce over the 16 partial maxes
    float m = 0.f;
    #pragma unroll
    for (int s = 0; s < NSUB; ++s) m = fmaxf(m, __uint_as_float(pmax[b * NSUB + s]));
    const float sb = sqrtf(m);

    // register-resident points (pairs, for v_pk_* fp32) + running distances
    float pxx[NPAIR], pxy[NPAIR], pyx[NPAIR], pyy[NPAIR],
          pzx[NPAIR], pzy[NPAIR], pdx[NPAIR], pdy[NPAIR];
    #pragma unroll
    for (int j = 0; j < NPAIR; ++j) {
        const int p0 = tl + (2 * j) * STRIDE;
        const int p1 = tl + (2 * j + 1) * STRIDE;
        const bool v0 = p0 < NPTS, v1 = p1 < NPTS;
        pxx[j] = v0 ? P[p0 * 3 + 0] : 0.f;  pxy[j] = v1 ? P[p1 * 3 + 0] : 0.f;
        pyx[j] = v0 ? P[p0 * 3 + 1] : 0.f;  pyy[j] = v1 ? P[p1 * 3 + 1] : 0.f;
        pzx[j] = v0 ? P[p0 * 3 + 2] : 0.f;  pzy[j] = v1 ? P[p1 * 3 + 2] : 0.f;
        pdx[j] = v0 ? 1e10f : -1.0f;        pdy[j] = v1 ? 1e10f : -1.0f;
        // every lane has >=24 valid points, so per-lane best is always >= 0
    }

    __shared__ u64 lds_key[WPB];
    __shared__ int lds_win;

    int cur = init_far[b];
    float cx = P[cur * 3 + 0], cy = P[cur * 3 + 1], cz = P[cur * 3 + 2];
    const bool wrblk = (g == 0);

    for (int i = 0; i < NPOINT; ++i) {
        if (i == NPOINT - 1) {
            if (wrblk && tid == 64) {
                float* o = out + ((size_t)b * NPOINT + i) * 4;
                o[0] = cmap[(size_t)b * NPTS + cur];
                o[1] = cx / sb; o[2] = cy / sb; o[3] = cz / sb;
            }
            break;
        }

        // ---- distance update + per-lane argmax (exact fp order match: no fma/contract) ----
        float best = -1.0f;
        int bidx = 0;
        {
            #pragma clang fp contract(off)
            #pragma unroll
            for (int j = 0; j < NPAIR; ++j) {
                float dx0 = pxx[j] - cx, dx1 = pxy[j] - cx;   // pairs -> v_pk_add_f32
                float dy0 = pyx[j] - cy, dy1 = pyy[j] - cy;
                float dz0 = pzx[j] - cz, dz1 = pzy[j] - cz;
                float s0 = dx0 * dx0 + dy0 * dy0;  float s1 = dx1 * dx1 + dy1 * dy1;
                s0 = s0 + dz0 * dz0;               s1 = s1 + dz1 * dz1;
                float n0 = fminf(pdx[j], s0);      float n1 = fminf(pdy[j], s1);
                pdx[j] = n0;                       pdy[j] = n1;
                if (n0 > best) { best = n0; bidx = tl + (2 * j) * STRIDE; }      // strict >
                if (n1 > best) { best = n1; bidx = tl + (2 * j + 1) * STRIDE; }  // => first max
            }
        }

        // ---- wave argmax (u64 butterfly) ----
        const u64 want = (u64)(i + 1);
        u64 key = ((u64)__float_as_uint(best) << 22) | (u64)(0x3FFFFFu - (unsigned)bidx);
        #pragma unroll
        for (int off = 32; off; off >>= 1) {
            u64 o2 = __shfl_xor(key, off);
            key = o2 > key ? o2 : key;
        }
        if (lane == 0) lds_key[wave] = key;
        __syncthreads();   // syncA

        u64* const bs = slots + ((size_t)(i & 1) * NBATCH + b) * GPB;

        if (wave == 0) {
            // block reduce (lanes 0..3, 2-hop), lane 0 publishes the slot
            u64 bk = (lane < WPB) ? lds_key[lane] : 0;
            #pragma unroll
            for (int off = 1; off < WPB; off <<= 1) {
                u64 o2 = __shfl_xor(bk, off);
                bk = o2 > bk ? o2 : bk;
            }
            if (lane == 0)
                __hip_atomic_store(&bs[g], bk | (want << 54),
                                   __ATOMIC_RELAXED, __HIP_MEMORY_SCOPE_AGENT);

            // poll: one atomic u64 load + one waitcnt per round, per-lane independent exit
            u64 v = 0;
            if (lane < GPB) {
                u64* sp = &bs[lane];
                int tries = 0;
                for (;;) {
                    v = __hip_atomic_load(sp, __ATOMIC_RELAXED, __HIP_MEMORY_SCOPE_AGENT);
                    if ((v >> 54) >= want) break;
                    if (++tries > 16) __builtin_amdgcn_s_sleep(1);
                }
            }
            #pragma unroll
            for (int off = 8; off; off >>= 1) {     // 4-hop argmax over the 16 gate words
                u64 o2 = __shfl_xor(v, off);
                v = o2 > v ? o2 : v;
            }
            if (lane == 0)
                lds_win = (int)(0x3FFFFFu - (unsigned)(v & 0x3FFFFFu));
        } else if (wave == 1 && wrblk && lane == 0) {
            // output row for centroid i — parallel with wave 0's store+poll (off critical path)
            float* o = out + ((size_t)b * NPOINT + i) * 4;
            o[0] = cmap[(size_t)b * NPTS + cur];
            o[1] = cx / sb; o[2] = cy / sb; o[3] = cz / sb;
        }
        __syncthreads();   // syncB
        cur = lds_win;
        cx = P[cur * 3 + 0];   // broadcast gather (L2-hot, ~0.1 us)
        cy = P[cur * 3 + 1];
        cz = P[cur * 3 + 2];
    }
}

extern "C" void kernel_launch(void* const* d_in, const int* in_sizes, int n_in,
                              void* d_out, int out_size, void* d_ws, size_t ws_size,
                              hipStream_t stream) {
    const float* mesh = (const float*)d_in[0];
    const float* cmap = (const float*)d_in[1];
    const int* init   = (const int*)d_in[2];
    float* out = (float*)d_out;

    char* ws      = (char*)d_ws;
    float* psum   = (float*)ws;
    unsigned* pmx = (unsigned*)(ws + 4096);
    u64* slots    = (u64*)(ws + 8192);

    sum_kernel<<<dim3(256), dim3(TPB), 0, stream>>>(mesh, psum);
    max_kernel<<<dim3(256), dim3(TPB), 0, stream>>>(mesh, psum, pmx, slots);
    fps_kernel<<<dim3(256), dim3(TPB), 0, stream>>>(mesh, cmap, init, pmx, slots, out);
}